// Round 15
// baseline (259.419 us; speedup 1.0000x reference)
//
#include <hip/hip_runtime.h>

#define DIM 1536
#define NH  12
#define HD  128
#define SEQ 4096

typedef unsigned short u16;
typedef unsigned int   u32;
typedef __attribute__((ext_vector_type(8))) short bf16x8;
typedef __attribute__((ext_vector_type(4))) float f32x4;
typedef __attribute__((ext_vector_type(16))) float f32x16;

static __device__ __forceinline__ u16 f2bf(float f) {
    u32 u = __float_as_uint(f);
    u32 r = u + 0x7FFFu + ((u >> 16) & 1u);
    return (u16)(r >> 16);
}
static __device__ __forceinline__ u32 pack2(float a, float b) {
    return (u32)f2bf(a) | ((u32)f2bf(b) << 16);
}

#define GLL(g, s) __builtin_amdgcn_global_load_lds( \
    (const __attribute__((address_space(1))) void*)(g), \
    (__attribute__((address_space(3))) void*)(s), 16, 0, 0)

// q pre-scale: 1/sqrt(128) * log2(e)
#define SCLQ 0.127532f

// ---------------- fused prep: x -> bf16 (blocks 0..3071) + cos/sin & bias (3072..4095) ----------------
__global__ __launch_bounds__(256) void k_prep(const float* __restrict__ x, u16* __restrict__ xb,
                                              const float* __restrict__ fr, const float* __restrict__ bq,
                                              const float* __restrict__ bk, const float* __restrict__ bv,
                                              float2* __restrict__ cs, float* __restrict__ bqkv) {
    int b = blockIdx.x;
    if (b < 3072) {
        int gid = b * 256 + threadIdx.x;           // 786432 threads
        const float4* p = (const float4*)x + (size_t)gid * 2;
        float4 a = p[0], c = p[1];
        uint4 o;
        o.x = pack2(a.x, a.y); o.y = pack2(a.z, a.w);
        o.z = pack2(c.x, c.y); o.w = pack2(c.z, c.w);
        *(uint4*)(xb + (size_t)gid * 8) = o;
    } else {
        int gid = (b - 3072) * 256 + threadIdx.x;  // 262144 threads
        float f = fr[gid];
        cs[gid] = make_float2(cosf(f), sinf(f));
        if (gid < 3 * DIM)
            bqkv[gid] = gid < DIM ? bq[gid] : gid < 2 * DIM ? bk[gid - DIM] : bv[gid - 2 * DIM];
    }
}

// ---------------- weight transpose + bf16 ----------------
__global__ __launch_bounds__(256) void k_transpose_w(const float* __restrict__ Wq, const float* __restrict__ Wk,
                                                     const float* __restrict__ Wv, const float* __restrict__ Wo,
                                                     u16* __restrict__ wqkv, u16* __restrict__ wot) {
    __shared__ float tile[32][33];
    int z = blockIdx.z;
    const float* W = z == 0 ? Wq : z == 1 ? Wk : z == 2 ? Wv : Wo;
    u16* out = z < 3 ? (wqkv + (size_t)z * DIM * DIM) : wot;
    int tx = threadIdx.x, ty = threadIdx.y;        // (32, 8)
    int c0 = blockIdx.x * 32, r0 = blockIdx.y * 32;
#pragma unroll
    for (int i = 0; i < 4; i++)
        tile[ty + i * 8][tx] = W[(size_t)(r0 + ty + i * 8) * DIM + c0 + tx];
    __syncthreads();
#pragma unroll
    for (int i = 0; i < 4; i++)
        out[(size_t)(c0 + ty + i * 8) * DIM + r0 + tx] = f2bf(tile[tx][ty + i * 8]);
}

// ---------------- GEMM: C = A @ B^T + bias (BM=128, BN=192, 2-phase dbuf) ----------------
// mode 0: fused epilogue -> q (rope+scale), k (rope), v (direct V^T write).
// mode 1: fp32 [M][DIM] output.
__global__ __launch_bounds__(256, 3) void k_gemm(const u16* __restrict__ A, const u16* __restrict__ B,
                                                 const float* __restrict__ bias, int Kdim, int mode,
                                                 const float2* __restrict__ cs2,
                                                 u16* __restrict__ qo, u16* __restrict__ ko,
                                                 u16* __restrict__ vto, float* __restrict__ outf) {
    __shared__ u16 As[2][128 * 32];
    __shared__ u16 Bs[2][192 * 32];
    const int tid = threadIdx.x;
    const int w = tid >> 6, l = tid & 63;
    const int wr = w >> 1, wc = w & 1;            // wave grid 2x2: 64 rows x 96 cols each
    const int lr = l & 15, lg = l >> 4;
    int nwg = gridDim.x * gridDim.y;
    int bid = blockIdx.y * gridDim.x + blockIdx.x;
    int swz = (bid & 7) * (nwg >> 3) + (bid >> 3);
    const int m0 = (swz / gridDim.x) * 128, n0 = (swz % gridDim.x) * 192;
    f32x4 acc[4][6] = {};

    const int srow = l >> 2;
    const int scol = (((l & 3) * 16) ^ (((l >> 2) & 3) << 4)) >> 1;
    const size_t Ab0 = (size_t)(m0 + (w * 2 + 0) * 16 + srow) * Kdim + scol;
    const size_t Ab1 = (size_t)(m0 + (w * 2 + 1) * 16 + srow) * Kdim + scol;
    const size_t Bb0 = (size_t)(n0 + (w * 3 + 0) * 16 + srow) * Kdim + scol;
    const size_t Bb1 = (size_t)(n0 + (w * 3 + 1) * 16 + srow) * Kdim + scol;
    const size_t Bb2 = (size_t)(n0 + (w * 3 + 2) * 16 + srow) * Kdim + scol;
    const int ao0 = (w * 2 + 0) * 512, ao1 = (w * 2 + 1) * 512;
    const int bo0 = (w * 3 + 0) * 512, bo1 = (w * 3 + 1) * 512, bo2 = (w * 3 + 2) * 512;

#define STAGE(buf, kt) do { \
        GLL(A + Ab0 + (kt), As[buf] + ao0); \
        GLL(A + Ab1 + (kt), As[buf] + ao1); \
        GLL(B + Bb0 + (kt), Bs[buf] + bo0); \
        GLL(B + Bb1 + (kt), Bs[buf] + bo1); \
        GLL(B + Bb2 + (kt), Bs[buf] + bo2); \
    } while (0)

    const int nk = Kdim >> 5;
    STAGE(0, 0);
    __syncthreads();

    int cur = 0;
    for (int t = 0; t < nk; ++t) {
        if (t + 1 < nk) STAGE(cur ^ 1, (t + 1) << 5);   // issue next tile before compute
        const u16* Ac = As[cur];
        const u16* Bc = Bs[cur];
        const int co = (lg * 8) ^ ((lr & 3) << 3);
        bf16x8 af[4], bg[6];
#pragma unroll
        for (int i = 0; i < 4; i++)
            af[i] = *(const bf16x8*)(Ac + (wr * 64 + i * 16 + lr) * 32 + co);
#pragma unroll
        for (int j = 0; j < 6; j++)
            bg[j] = *(const bf16x8*)(Bc + (wc * 96 + j * 16 + lr) * 32 + co);
#pragma unroll
        for (int i = 0; i < 4; i++)
#pragma unroll
            for (int j = 0; j < 6; j++)
                acc[i][j] = __builtin_amdgcn_mfma_f32_16x16x32_bf16(af[i], bg[j], acc[i][j], 0, 0, 0);
        __syncthreads();   // drains prefetch + guards buffer swap
        cur ^= 1;
    }
#undef STAGE

#pragma unroll
    for (int j = 0; j < 6; j++) {
        int gc = n0 + wc * 96 + j * 16 + lr;
        float bb = bias[gc];
#pragma unroll
        for (int i = 0; i < 4; i++) {
            int gr0 = m0 + wr * 64 + i * 16 + lg * 4;
            if (mode == 0) {
                int t = gc / DIM;              // uniform within block (192 | 1536)
                int rr = gc % DIM;
                int hh = rr >> 7, hd = rr & 127;
                if (t == 2) {
                    // V^T: vt[hh][hd][row], 4 consecutive rows -> one 8B store
                    u16* dst = vto + ((size_t)hh * HD + hd) * SEQ + gr0;
                    ushort4 pk;
                    pk.x = f2bf(acc[i][j][0] + bb);
                    pk.y = f2bf(acc[i][j][1] + bb);
                    pk.z = f2bf(acc[i][j][2] + bb);
                    pk.w = f2bf(acc[i][j][3] + bb);
                    *(ushort4*)dst = pk;
                } else {
                    // q/k with fused RoPE (pair partner = lane l^1), q also * SCLQ
                    bool odd = gc & 1;
                    u16* dst = (t == 0 ? qo : ko) + (size_t)hh * SEQ * HD + hd;
                    const float2* cp = cs2 + (hd >> 1);
#pragma unroll
                    for (int r = 0; r < 4; r++) {
                        float v = acc[i][j][r] + bb;
                        float vp = __shfl_xor(v, 1);
                        float2 c = cp[(size_t)(gr0 + r) * 64];
                        float o = odd ? fmaf(vp, c.y, v * c.x)     // x0*s + x1*c
                                      : fmaf(v, c.x, -vp * c.y);   // x0*c - x1*s
                        if (t == 0) o *= SCLQ;
                        dst[(size_t)(gr0 + r) * HD] = f2bf(o);
                    }
                }
            } else {
#pragma unroll
                for (int r = 0; r < 4; r++)
                    outf[(size_t)(gr0 + r) * DIM + gc] = acc[i][j][r] + bb;
            }
        }
    }
}

// ---------------- flash attention (32x32 MFMA, split-K, GLL split-wait staging) ----------------
// r8/r12 structure, but staging waits are split: K's 4 GLLs retire (vmcnt(4))
// before QK; V's 4 ride in flight under QK+softmax and drain (vmcnt(0)) only
// before PV. Same LDS/regs/occupancy as the validated 131us kernel.
__global__ __launch_bounds__(256, 3) void k_attn(const u16* __restrict__ qb, const u16* __restrict__ kbuf,
                                                 const u16* __restrict__ vt, u16* __restrict__ attnb) {
    __shared__ u16 Ks[64 * 128];      // swizzled: phys(row,b) = row*256 + (b ^ ((row&7)<<4))
    __shared__ u16 Vs[128 * 64];      // V^T: phys(row,b) = row*128 + (b ^ ((row&7)<<4))
    __shared__ float MB[128][18];     // dedicated split-K merge buffer
    const int tid = threadIdx.x;
    const int w = tid >> 6, l = tid & 63;
    const int qh = w & 1, kh = w >> 1;
    const int g = l >> 5, qlane = l & 31;
    const int lr = l & 15, lg = l >> 4;
    // XCD swizzle: 768 blocks = 8 XCD x 96
    int bid = blockIdx.x;
    int gw = (bid & 7) * 96 + (bid >> 3);
    const int h = gw >> 6;
    const int q0 = (gw & 63) << 6;
    const size_t hb = (size_t)h * SEQ * HD;
    constexpr float THR = 5.0f;

    // staging constants
    const int vrow8 = l >> 3;
    const int vc0 = (((l & 7) * 16) ^ (vrow8 << 4)) >> 1;

    // Q fragments (B-operand): lane holds Q[q0+qh*32+qlane][s*16 + g*8 + 0..7]
    bf16x8 qf[8];
    {
        const u16* qp = qb + hb + (size_t)(q0 + qh * 32 + qlane) * HD + g * 8;
#pragma unroll
        for (int s = 0; s < 8; s++)
            qf[s] = *(const bf16x8*)(qp + s * 16);
    }
    f32x16 O[4] = {};     // O^T: col=q=lane&31, rows(d) via reg mapping
    float m_run = -1e30f, lsum = 0.f;

    const int krow = kh * 32 + qlane;     // K A-frag row (key within tile)
    const int ksw = (krow & 7) << 4;
    const int vswl = (qlane & 7) << 4;    // V A-frag row swizzle (d & 7)

    for (int kt = 0; kt < SEQ; kt += 64) {
        // stage K first (4 GLLs), then V (4 GLLs); buffers free (loop-end barrier)
#pragma unroll
        for (int c = 0; c < 4; c++) {
            int cc = w * 4 + c;
            int key = cc * 4 + lg;
            int kd0 = ((lr * 16) ^ ((key & 7) << 4)) >> 1;
            GLL(kbuf + hb + (size_t)(kt + key) * HD + kd0, Ks + cc * 512);
        }
#pragma unroll
        for (int c = 0; c < 4; c++) {
            int cc = w * 4 + c;
            int dd = cc * 8 + vrow8;
            GLL(vt + hb + (size_t)dd * SEQ + kt + vc0, Vs + cc * 512);
        }
        asm volatile("s_waitcnt vmcnt(4)" ::: "memory");   // this wave's K landed (in-order)
        __builtin_amdgcn_sched_barrier(0);
        __builtin_amdgcn_s_barrier();                      // all waves' K landed
        asm volatile("" ::: "memory");

        // S^T = K @ Q^T : ST col=q, rows=keys (16 regs). V still in flight.
        f32x16 ST = {};
        const u16* Kp = Ks + krow * 128;
#pragma unroll
        for (int s = 0; s < 8; s++) {
            bf16x8 kf = *(const bf16x8*)(Kp + (((s * 32 + g * 16) ^ ksw) >> 1));
            ST = __builtin_amdgcn_mfma_f32_32x32x16_bf16(kf, qf[s], ST, 0, 0, 0);
        }

        // online softmax (q pre-scaled: scores already in log2 units)
        float mx = ST[0];
#pragma unroll
        for (int r = 1; r < 16; r++) mx = fmaxf(mx, ST[r]);
        mx = fmaxf(mx, __shfl_xor(mx, 32));
        bool grow = mx > m_run + THR;
        float m_new = grow ? mx : m_run;
        if (__any(grow)) {
            float alpha = grow ? __builtin_amdgcn_exp2f(m_run - m_new) : 1.0f;
            lsum *= alpha;
            m_run = m_new;
#pragma unroll
            for (int db = 0; db < 4; db++)
#pragma unroll
                for (int r = 0; r < 16; r++) O[db][r] *= alpha;
        }
        float ps = 0.f;
#pragma unroll
        for (int r = 0; r < 16; r++) {
            float p = __builtin_amdgcn_exp2f(ST[r] - m_new);
            ST[r] = p; ps += p;
        }
        lsum += ps;

        // pack P -> bf16 pairs; build PV B-frags in-register via permlane32_swap
        u32 pw[2][4];
#pragma unroll
        for (int s2 = 0; s2 < 2; s2++) {
            int rb = s2 * 8;
            u32 a, b2, c2, d2;
            asm("v_cvt_pk_bf16_f32 %0, %1, %2" : "=v"(a)  : "v"(ST[rb + 0]), "v"(ST[rb + 1]));
            asm("v_cvt_pk_bf16_f32 %0, %1, %2" : "=v"(b2) : "v"(ST[rb + 2]), "v"(ST[rb + 3]));
            asm("v_cvt_pk_bf16_f32 %0, %1, %2" : "=v"(c2) : "v"(ST[rb + 4]), "v"(ST[rb + 5]));
            asm("v_cvt_pk_bf16_f32 %0, %1, %2" : "=v"(d2) : "v"(ST[rb + 6]), "v"(ST[rb + 7]));
            asm("v_permlane32_swap_b32 %0, %1" : "+v"(a), "+v"(c2));
            asm("v_permlane32_swap_b32 %0, %1" : "+v"(b2), "+v"(d2));
            pw[s2][0] = a; pw[s2][1] = b2; pw[s2][2] = c2; pw[s2][3] = d2;
        }

        asm volatile("s_waitcnt vmcnt(0)" ::: "memory");   // V landed
        __builtin_amdgcn_sched_barrier(0);
        __builtin_amdgcn_s_barrier();                      // all waves' V landed
        asm volatile("" ::: "memory");

        // O^T += V^T-frag @ P-frag
#pragma unroll
        for (int s2 = 0; s2 < 2; s2++) {
            union { u32 u[4]; bf16x8 v; } pf;
            pf.u[0] = pw[s2][0]; pf.u[1] = pw[s2][1]; pf.u[2] = pw[s2][2]; pf.u[3] = pw[s2][3];
            int kb2 = kh * 64 + s2 * 32 + g * 16;
#pragma unroll
            for (int db = 0; db < 4; db++) {
                int d = db * 32 + qlane;
                bf16x8 vf = *(const bf16x8*)(Vs + d * 64 + ((kb2 ^ vswl) >> 1));
                O[db] = __builtin_amdgcn_mfma_f32_32x32x16_bf16(vf, pf.v, O[db], 0, 0, 0);
            }
        }

        asm volatile("" ::: "memory");
        __builtin_amdgcn_s_barrier();                      // all reads done before next stage
        asm volatile("" ::: "memory");
    }

    lsum += __shfl_xor(lsum, 32);

    // split-K merge via dedicated LDS buffer, chunked with paired barriers
    const int row = qh * 64 + l;
    u16* op = attnb + (size_t)(q0 + qh * 32 + qlane) * DIM + h * HD;
    __syncthreads();
    if (kh == 1) { MB[row][16] = m_run; MB[row][17] = lsum; }
    __syncthreads();
    float a0 = 0.f, a1 = 0.f;
    if (kh == 0) {
        float m1 = MB[row][16], l1 = MB[row][17];
        float mM = fmaxf(m_run, m1);
        a0 = __builtin_amdgcn_exp2f(m_run - mM);
        a1 = __builtin_amdgcn_exp2f(m1 - mM);
        float linv = 1.0f / (lsum * a0 + l1 * a1);
        a0 *= linv; a1 *= linv;
    }
#pragma unroll
    for (int db = 0; db < 4; db++) {
        __syncthreads();
        if (kh == 1) {
#pragma unroll
            for (int r = 0; r < 16; r++) MB[row][r] = O[db][r];
        }
        __syncthreads();
        if (kh == 0) {
#pragma unroll
            for (int r = 0; r < 16; r++) {
                int d = db * 32 + (r & 3) + 8 * (r >> 2) + 4 * g;
                op[d] = f2bf(O[db][r] * a0 + MB[row][r] * a1);
            }
        }
    }
}

extern "C" void kernel_launch(void* const* d_in, const int* in_sizes, int n_in,
                              void* d_out, int out_size, void* d_ws, size_t ws_size,
                              hipStream_t stream) {
    (void)in_sizes; (void)n_in; (void)out_size; (void)ws_size;
    const float* x  = (const float*)d_in[0];
    const float* fr = (const float*)d_in[1];
    const float* Wq = (const float*)d_in[2];
    const float* bq = (const float*)d_in[3];
    const float* Wk = (const float*)d_in[4];
    const float* bk = (const float*)d_in[5];
    const float* Wv = (const float*)d_in[6];
    const float* bv = (const float*)d_in[7];
    const float* Wo = (const float*)d_in[8];
    const float* bo = (const float*)d_in[9];
    float* out = (float*)d_out;

    char* ws = (char*)d_ws;
    size_t off = 0;
    auto alloc = [&](size_t b) { char* p = ws + off; off = (off + b + 255) & ~(size_t)255; return p; };
    u16*   xb    = (u16*)alloc((size_t)SEQ * DIM * 2);
    u16*   wqkv  = (u16*)alloc((size_t)3 * DIM * DIM * 2);
    u16*   wot   = (u16*)alloc((size_t)DIM * DIM * 2);
    float* bqkv  = (float*)alloc((size_t)3 * DIM * 4);
    u16*   qb    = (u16*)alloc((size_t)SEQ * DIM * 2);
    u16*   kb    = (u16*)alloc((size_t)SEQ * DIM * 2);
    u16*   vtb   = (u16*)alloc((size_t)SEQ * DIM * 2);
    u16*   attnb = (u16*)alloc((size_t)SEQ * DIM * 2);
    float2* cs   = (float2*)alloc((size_t)SEQ * 64 * 8);

    k_prep<<<4096, 256, 0, stream>>>(x, xb, fr, bq, bk, bv, cs, bqkv);
    k_transpose_w<<<dim3(48, 48, 4), dim3(32, 8), 0, stream>>>(Wq, Wk, Wv, Wo, wqkv, wot);
    k_gemm<<<dim3(24, 32), 256, 0, stream>>>(xb, wqkv, bqkv, DIM, 0, cs, qb, kb, vtb, nullptr);
    k_attn<<<768, 256, 0, stream>>>(qb, kb, vtb, attnb);
    k_gemm<<<dim3(8, 32), 256, 0, stream>>>(attnb, wot, bo, DIM, 1, nullptr, nullptr, nullptr, nullptr, out);
}

// Round 16
// 257.179 us; speedup vs baseline: 1.0087x; 1.0087x over previous
//
#include <hip/hip_runtime.h>

#define DIM 1536
#define NH  12
#define HD  128
#define SEQ 4096

typedef unsigned short u16;
typedef unsigned int   u32;
typedef __attribute__((ext_vector_type(8))) short bf16x8;
typedef __attribute__((ext_vector_type(4))) float f32x4;
typedef __attribute__((ext_vector_type(16))) float f32x16;

static __device__ __forceinline__ u16 f2bf(float f) {
    u32 u = __float_as_uint(f);
    u32 r = u + 0x7FFFu + ((u >> 16) & 1u);
    return (u16)(r >> 16);
}
static __device__ __forceinline__ u32 pack2(float a, float b) {
    return (u32)f2bf(a) | ((u32)f2bf(b) << 16);
}

#define GLL(g, s) __builtin_amdgcn_global_load_lds( \
    (const __attribute__((address_space(1))) void*)(g), \
    (__attribute__((address_space(3))) void*)(s), 16, 0, 0)

// q pre-scale: 1/sqrt(128) * log2(e)
#define SCLQ 0.127532f

// ---------------- fused prep: x -> bf16 (blocks 0..3071) + cos/sin & bias (3072..4095) ----------------
__global__ __launch_bounds__(256) void k_prep(const float* __restrict__ x, u16* __restrict__ xb,
                                              const float* __restrict__ fr, const float* __restrict__ bq,
                                              const float* __restrict__ bk, const float* __restrict__ bv,
                                              float2* __restrict__ cs, float* __restrict__ bqkv) {
    int b = blockIdx.x;
    if (b < 3072) {
        int gid = b * 256 + threadIdx.x;           // 786432 threads
        const float4* p = (const float4*)x + (size_t)gid * 2;
        float4 a = p[0], c = p[1];
        uint4 o;
        o.x = pack2(a.x, a.y); o.y = pack2(a.z, a.w);
        o.z = pack2(c.x, c.y); o.w = pack2(c.z, c.w);
        *(uint4*)(xb + (size_t)gid * 8) = o;
    } else {
        int gid = (b - 3072) * 256 + threadIdx.x;  // 262144 threads
        float f = fr[gid];
        cs[gid] = make_float2(cosf(f), sinf(f));
        if (gid < 3 * DIM)
            bqkv[gid] = gid < DIM ? bq[gid] : gid < 2 * DIM ? bk[gid - DIM] : bv[gid - 2 * DIM];
    }
}

// ---------------- weight transpose + bf16 ----------------
__global__ __launch_bounds__(256) void k_transpose_w(const float* __restrict__ Wq, const float* __restrict__ Wk,
                                                     const float* __restrict__ Wv, const float* __restrict__ Wo,
                                                     u16* __restrict__ wqkv, u16* __restrict__ wot) {
    __shared__ float tile[32][33];
    int z = blockIdx.z;
    const float* W = z == 0 ? Wq : z == 1 ? Wk : z == 2 ? Wv : Wo;
    u16* out = z < 3 ? (wqkv + (size_t)z * DIM * DIM) : wot;
    int tx = threadIdx.x, ty = threadIdx.y;        // (32, 8)
    int c0 = blockIdx.x * 32, r0 = blockIdx.y * 32;
#pragma unroll
    for (int i = 0; i < 4; i++)
        tile[ty + i * 8][tx] = W[(size_t)(r0 + ty + i * 8) * DIM + c0 + tx];
    __syncthreads();
#pragma unroll
    for (int i = 0; i < 4; i++)
        out[(size_t)(c0 + ty + i * 8) * DIM + r0 + tx] = f2bf(tile[tx][ty + i * 8]);
}

// ---------------- GEMM: C = A @ B^T + bias (BM=128, BN=192, 2-phase dbuf) ----------------
// mode 0: fused epilogue -> q (rope+scale), k (rope), v (direct V^T write).
// mode 1: fp32 [M][DIM] output.
__global__ __launch_bounds__(256, 3) void k_gemm(const u16* __restrict__ A, const u16* __restrict__ B,
                                                 const float* __restrict__ bias, int Kdim, int mode,
                                                 const float2* __restrict__ cs2,
                                                 u16* __restrict__ qo, u16* __restrict__ ko,
                                                 u16* __restrict__ vto, float* __restrict__ outf) {
    __shared__ u16 As[2][128 * 32];
    __shared__ u16 Bs[2][192 * 32];
    const int tid = threadIdx.x;
    const int w = tid >> 6, l = tid & 63;
    const int wr = w >> 1, wc = w & 1;            // wave grid 2x2: 64 rows x 96 cols each
    const int lr = l & 15, lg = l >> 4;
    int nwg = gridDim.x * gridDim.y;
    int bid = blockIdx.y * gridDim.x + blockIdx.x;
    int swz = (bid & 7) * (nwg >> 3) + (bid >> 3);
    const int m0 = (swz / gridDim.x) * 128, n0 = (swz % gridDim.x) * 192;
    f32x4 acc[4][6] = {};

    const int srow = l >> 2;
    const int scol = (((l & 3) * 16) ^ (((l >> 2) & 3) << 4)) >> 1;
    const size_t Ab0 = (size_t)(m0 + (w * 2 + 0) * 16 + srow) * Kdim + scol;
    const size_t Ab1 = (size_t)(m0 + (w * 2 + 1) * 16 + srow) * Kdim + scol;
    const size_t Bb0 = (size_t)(n0 + (w * 3 + 0) * 16 + srow) * Kdim + scol;
    const size_t Bb1 = (size_t)(n0 + (w * 3 + 1) * 16 + srow) * Kdim + scol;
    const size_t Bb2 = (size_t)(n0 + (w * 3 + 2) * 16 + srow) * Kdim + scol;
    const int ao0 = (w * 2 + 0) * 512, ao1 = (w * 2 + 1) * 512;
    const int bo0 = (w * 3 + 0) * 512, bo1 = (w * 3 + 1) * 512, bo2 = (w * 3 + 2) * 512;

#define STAGE(buf, kt) do { \
        GLL(A + Ab0 + (kt), As[buf] + ao0); \
        GLL(A + Ab1 + (kt), As[buf] + ao1); \
        GLL(B + Bb0 + (kt), Bs[buf] + bo0); \
        GLL(B + Bb1 + (kt), Bs[buf] + bo1); \
        GLL(B + Bb2 + (kt), Bs[buf] + bo2); \
    } while (0)

    const int nk = Kdim >> 5;
    STAGE(0, 0);
    __syncthreads();

    int cur = 0;
    for (int t = 0; t < nk; ++t) {
        if (t + 1 < nk) STAGE(cur ^ 1, (t + 1) << 5);   // issue next tile before compute
        const u16* Ac = As[cur];
        const u16* Bc = Bs[cur];
        const int co = (lg * 8) ^ ((lr & 3) << 3);
        bf16x8 af[4], bg[6];
#pragma unroll
        for (int i = 0; i < 4; i++)
            af[i] = *(const bf16x8*)(Ac + (wr * 64 + i * 16 + lr) * 32 + co);
#pragma unroll
        for (int j = 0; j < 6; j++)
            bg[j] = *(const bf16x8*)(Bc + (wc * 96 + j * 16 + lr) * 32 + co);
#pragma unroll
        for (int i = 0; i < 4; i++)
#pragma unroll
            for (int j = 0; j < 6; j++)
                acc[i][j] = __builtin_amdgcn_mfma_f32_16x16x32_bf16(af[i], bg[j], acc[i][j], 0, 0, 0);
        __syncthreads();   // drains prefetch + guards buffer swap
        cur ^= 1;
    }
#undef STAGE

#pragma unroll
    for (int j = 0; j < 6; j++) {
        int gc = n0 + wc * 96 + j * 16 + lr;
        float bb = bias[gc];
#pragma unroll
        for (int i = 0; i < 4; i++) {
            int gr0 = m0 + wr * 64 + i * 16 + lg * 4;
            if (mode == 0) {
                int t = gc / DIM;              // uniform within block (192 | 1536)
                int rr = gc % DIM;
                int hh = rr >> 7, hd = rr & 127;
                if (t == 2) {
                    // V^T: vt[hh][hd][row], 4 consecutive rows -> one 8B store
                    u16* dst = vto + ((size_t)hh * HD + hd) * SEQ + gr0;
                    ushort4 pk;
                    pk.x = f2bf(acc[i][j][0] + bb);
                    pk.y = f2bf(acc[i][j][1] + bb);
                    pk.z = f2bf(acc[i][j][2] + bb);
                    pk.w = f2bf(acc[i][j][3] + bb);
                    *(ushort4*)dst = pk;
                } else {
                    // q/k with fused RoPE (pair partner = lane l^1), q also * SCLQ
                    bool odd = gc & 1;
                    u16* dst = (t == 0 ? qo : ko) + (size_t)hh * SEQ * HD + hd;
                    const float2* cp = cs2 + (hd >> 1);
#pragma unroll
                    for (int r = 0; r < 4; r++) {
                        float v = acc[i][j][r] + bb;
                        float vp = __shfl_xor(v, 1);
                        float2 c = cp[(size_t)(gr0 + r) * 64];
                        float o = odd ? fmaf(vp, c.y, v * c.x)     // x0*s + x1*c
                                      : fmaf(v, c.x, -vp * c.y);   // x0*c - x1*s
                        if (t == 0) o *= SCLQ;
                        dst[(size_t)(gr0 + r) * HD] = f2bf(o);
                    }
                }
            } else {
#pragma unroll
                for (int r = 0; r < 4; r++)
                    outf[(size_t)(gr0 + r) * DIM + gc] = acc[i][j][r] + bb;
            }
        }
    }
}

// ---------------- flash attention (32x32 MFMA, split-K, GLL single-buffer) ----------------
// r8/r12/r14-validated structure (131 us, reproduced 5x); q pre-scaled softmax.
__global__ __launch_bounds__(256, 3) void k_attn(const u16* __restrict__ qb, const u16* __restrict__ kbuf,
                                                 const u16* __restrict__ vt, u16* __restrict__ attnb) {
    __shared__ u16 Ks[64 * 128];      // swizzled: phys(row,b) = row*256 + (b ^ ((row&7)<<4))
    __shared__ u16 Vs[128 * 64];      // V^T: phys(row,b) = row*128 + (b ^ ((row&7)<<4))
    __shared__ float MB[128][18];     // dedicated split-K merge buffer
    const int tid = threadIdx.x;
    const int w = tid >> 6, l = tid & 63;
    const int qh = w & 1, kh = w >> 1;
    const int g = l >> 5, qlane = l & 31;
    const int lr = l & 15, lg = l >> 4;
    // XCD swizzle: 768 blocks = 8 XCD x 96
    int bid = blockIdx.x;
    int gw = (bid & 7) * 96 + (bid >> 3);
    const int h = gw >> 6;
    const int q0 = (gw & 63) << 6;
    const size_t hb = (size_t)h * SEQ * HD;
    constexpr float THR = 5.0f;

    // staging constants
    const int vrow8 = l >> 3;
    const int vc0 = (((l & 7) * 16) ^ (vrow8 << 4)) >> 1;

    // Q fragments (B-operand): lane holds Q[q0+qh*32+qlane][s*16 + g*8 + 0..7]
    bf16x8 qf[8];
    {
        const u16* qp = qb + hb + (size_t)(q0 + qh * 32 + qlane) * HD + g * 8;
#pragma unroll
        for (int s = 0; s < 8; s++)
            qf[s] = *(const bf16x8*)(qp + s * 16);
    }
    f32x16 O[4] = {};     // O^T: col=q=lane&31, rows(d) via reg mapping
    float m_run = -1e30f, lsum = 0.f;

    const int krow = kh * 32 + qlane;     // K A-frag row (key within tile)
    const int ksw = (krow & 7) << 4;
    const int vswl = (qlane & 7) << 4;    // V A-frag row swizzle (d & 7)

    for (int kt = 0; kt < SEQ; kt += 64) {
        __syncthreads();
#pragma unroll
        for (int c = 0; c < 4; c++) {
            int cc = w * 4 + c;
            int key = cc * 4 + lg;
            int kd0 = ((lr * 16) ^ ((key & 7) << 4)) >> 1;
            GLL(kbuf + hb + (size_t)(kt + key) * HD + kd0, Ks + cc * 512);
            int dd = cc * 8 + vrow8;
            GLL(vt + hb + (size_t)dd * SEQ + kt + vc0, Vs + cc * 512);
        }
        __syncthreads();

        // S^T = K @ Q^T : ST col=q, rows=keys (16 regs)
        f32x16 ST = {};
        const u16* Kp = Ks + krow * 128;
#pragma unroll
        for (int s = 0; s < 8; s++) {
            bf16x8 kf = *(const bf16x8*)(Kp + (((s * 32 + g * 16) ^ ksw) >> 1));
            ST = __builtin_amdgcn_mfma_f32_32x32x16_bf16(kf, qf[s], ST, 0, 0, 0);
        }

        // online softmax (q pre-scaled: scores already in log2 units)
        float mx = ST[0];
#pragma unroll
        for (int r = 1; r < 16; r++) mx = fmaxf(mx, ST[r]);
        mx = fmaxf(mx, __shfl_xor(mx, 32));
        bool grow = mx > m_run + THR;
        float m_new = grow ? mx : m_run;
        if (__any(grow)) {
            float alpha = grow ? __builtin_amdgcn_exp2f(m_run - m_new) : 1.0f;
            lsum *= alpha;
            m_run = m_new;
#pragma unroll
            for (int db = 0; db < 4; db++)
#pragma unroll
                for (int r = 0; r < 16; r++) O[db][r] *= alpha;
        }
        float ps = 0.f;
#pragma unroll
        for (int r = 0; r < 16; r++) {
            float p = __builtin_amdgcn_exp2f(ST[r] - m_new);
            ST[r] = p; ps += p;
        }
        lsum += ps;

        // pack P -> bf16 pairs; build PV B-frags in-register via permlane32_swap
        u32 pw[2][4];
#pragma unroll
        for (int s2 = 0; s2 < 2; s2++) {
            int rb = s2 * 8;
            u32 a, b2, c2, d2;
            asm("v_cvt_pk_bf16_f32 %0, %1, %2" : "=v"(a)  : "v"(ST[rb + 0]), "v"(ST[rb + 1]));
            asm("v_cvt_pk_bf16_f32 %0, %1, %2" : "=v"(b2) : "v"(ST[rb + 2]), "v"(ST[rb + 3]));
            asm("v_cvt_pk_bf16_f32 %0, %1, %2" : "=v"(c2) : "v"(ST[rb + 4]), "v"(ST[rb + 5]));
            asm("v_cvt_pk_bf16_f32 %0, %1, %2" : "=v"(d2) : "v"(ST[rb + 6]), "v"(ST[rb + 7]));
            asm("v_permlane32_swap_b32 %0, %1" : "+v"(a), "+v"(c2));
            asm("v_permlane32_swap_b32 %0, %1" : "+v"(b2), "+v"(d2));
            pw[s2][0] = a; pw[s2][1] = b2; pw[s2][2] = c2; pw[s2][3] = d2;
        }

        // O^T += V^T-frag @ P-frag
#pragma unroll
        for (int s2 = 0; s2 < 2; s2++) {
            union { u32 u[4]; bf16x8 v; } pf;
            pf.u[0] = pw[s2][0]; pf.u[1] = pw[s2][1]; pf.u[2] = pw[s2][2]; pf.u[3] = pw[s2][3];
            int kb2 = kh * 64 + s2 * 32 + g * 16;
#pragma unroll
            for (int db = 0; db < 4; db++) {
                int d = db * 32 + qlane;
                bf16x8 vf = *(const bf16x8*)(Vs + d * 64 + ((kb2 ^ vswl) >> 1));
                O[db] = __builtin_amdgcn_mfma_f32_32x32x16_bf16(vf, pf.v, O[db], 0, 0, 0);
            }
        }
    }

    lsum += __shfl_xor(lsum, 32);

    // split-K merge via dedicated LDS buffer, chunked with paired barriers
    const int row = qh * 64 + l;
    u16* op = attnb + (size_t)(q0 + qh * 32 + qlane) * DIM + h * HD;
    __syncthreads();
    if (kh == 1) { MB[row][16] = m_run; MB[row][17] = lsum; }
    __syncthreads();
    float a0 = 0.f, a1 = 0.f;
    if (kh == 0) {
        float m1 = MB[row][16], l1 = MB[row][17];
        float mM = fmaxf(m_run, m1);
        a0 = __builtin_amdgcn_exp2f(m_run - mM);
        a1 = __builtin_amdgcn_exp2f(m1 - mM);
        float linv = 1.0f / (lsum * a0 + l1 * a1);
        a0 *= linv; a1 *= linv;
    }
#pragma unroll
    for (int db = 0; db < 4; db++) {
        __syncthreads();
        if (kh == 1) {
#pragma unroll
            for (int r = 0; r < 16; r++) MB[row][r] = O[db][r];
        }
        __syncthreads();
        if (kh == 0) {
#pragma unroll
            for (int r = 0; r < 16; r++) {
                int d = db * 32 + (r & 3) + 8 * (r >> 2) + 4 * g;
                op[d] = f2bf(O[db][r] * a0 + MB[row][r] * a1);
            }
        }
    }
}

extern "C" void kernel_launch(void* const* d_in, const int* in_sizes, int n_in,
                              void* d_out, int out_size, void* d_ws, size_t ws_size,
                              hipStream_t stream) {
    (void)in_sizes; (void)n_in; (void)out_size; (void)ws_size;
    const float* x  = (const float*)d_in[0];
    const float* fr = (const float*)d_in[1];
    const float* Wq = (const float*)d_in[2];
    const float* bq = (const float*)d_in[3];
    const float* Wk = (const float*)d_in[4];
    const float* bk = (const float*)d_in[5];
    const float* Wv = (const float*)d_in[6];
    const float* bv = (const float*)d_in[7];
    const float* Wo = (const float*)d_in[8];
    const float* bo = (const float*)d_in[9];
    float* out = (float*)d_out;

    char* ws = (char*)d_ws;
    size_t off = 0;
    auto alloc = [&](size_t b) { char* p = ws + off; off = (off + b + 255) & ~(size_t)255; return p; };
    u16*   xb    = (u16*)alloc((size_t)SEQ * DIM * 2);
    u16*   wqkv  = (u16*)alloc((size_t)3 * DIM * DIM * 2);
    u16*   wot   = (u16*)alloc((size_t)DIM * DIM * 2);
    float* bqkv  = (float*)alloc((size_t)3 * DIM * 4);
    u16*   qb    = (u16*)alloc((size_t)SEQ * DIM * 2);
    u16*   kb    = (u16*)alloc((size_t)SEQ * DIM * 2);
    u16*   vtb   = (u16*)alloc((size_t)SEQ * DIM * 2);
    u16*   attnb = (u16*)alloc((size_t)SEQ * DIM * 2);
    float2* cs   = (float2*)alloc((size_t)SEQ * 64 * 8);

    k_prep<<<4096, 256, 0, stream>>>(x, xb, fr, bq, bk, bv, cs, bqkv);
    k_transpose_w<<<dim3(48, 48, 4), dim3(32, 8), 0, stream>>>(Wq, Wk, Wv, Wo, wqkv, wot);
    k_gemm<<<dim3(24, 32), 256, 0, stream>>>(xb, wqkv, bqkv, DIM, 0, cs, qb, kb, vtb, nullptr);
    k_attn<<<768, 256, 0, stream>>>(qb, kb, vtb, attnb);
    k_gemm<<<dim3(8, 32), 256, 0, stream>>>(attnb, wot, bo, DIM, 1, nullptr, nullptr, nullptr, nullptr, out);
}